// Round 8
// baseline (294.926 us; speedup 1.0000x reference)
//
#include <hip/hip_runtime.h>
#include <hip/hip_bf16.h>

#define NPER 24
#define B_ 32
#define N_ 1024
#define F_ 128
#define H_ 64
#define E_ 16

typedef __attribute__((ext_vector_type(8))) short short8;
typedef __attribute__((ext_vector_type(4))) float f32x4;

static __device__ __forceinline__ unsigned short f2bf(float x) {
    union { float f; unsigned u; } v; v.f = x;
    unsigned r = v.u + 0x7fffu + ((v.u >> 16) & 1u);   // RNE
    return (unsigned short)(r >> 16);
}
static __device__ __forceinline__ float bf2f(unsigned short h) {
    union { unsigned u; float f; } v; v.u = ((unsigned)h) << 16; return v.f;
}
static __device__ __forceinline__ unsigned short f2bf_hw(float x) {
    __hip_bfloat16 h = __float2bfloat16(x);
    return *(unsigned short*)&h;
}

// ---------------------------------------------------------------------------
// P1: all prep in one launch.  [r7-verified]
// ---------------------------------------------------------------------------
__global__ __launch_bounds__(256) void prep_all(
    const float* __restrict__ src_emb, const float* __restrict__ tgt_emb,
    const float* __restrict__ env_features, const float* __restrict__ env_W,
    const float* __restrict__ env_b,
    const float* __restrict__ adj, const float* __restrict__ W,
    const float* __restrict__ rW,
    unsigned short* __restrict__ src_bf, unsigned short* __restrict__ tgt_bf,
    unsigned short* __restrict__ adj_bf, unsigned short* __restrict__ Wt,
    unsigned short* __restrict__ rWt)
{
    const int bid = blockIdx.x;
    if (bid < 256) {
        const int idx = bid * 256 + threadIdx.x;   // 0..65535
        const int n = idx >> 6, h = idx & 63;
        float e = env_b[h];
#pragma unroll
        for (int k = 0; k < E_; ++k)
            e = fmaf(env_features[n * E_ + k], env_W[k * H_ + h], e);
        e = fmaxf(e, 0.f);
#pragma unroll 4
        for (int p = 0; p < NPER; ++p) {
            const size_t off = (size_t)p * (N_ * H_) + idx;
            src_bf[off] = f2bf(src_emb[off] + e);
            tgt_bf[off] = f2bf(tgt_emb[off] + e);
        }
    } else if (bid < 1280) {
        const size_t i = ((size_t)(bid - 256) * 256 + threadIdx.x) * 4;
        float4 v = *(const float4*)(adj + i);
        ushort4 o;
        o.x = f2bf(v.x); o.y = f2bf(v.y); o.z = f2bf(v.z); o.w = f2bf(v.w);
        *(ushort4*)(adj_bf + i) = o;
    } else {
        const int idx = (bid - 1280) * 256 + threadIdx.x;   // 0..32767
        const int which = idx >> 14, j = idx & 16383;
        const int f = j >> 7, d = j & 127;
        if (which == 0) Wt[f * 128 + d]  = f2bf(W[d * 128 + f]);
        else            rWt[f * 128 + d] = f2bf(rW[d * 128 + f]);
    }
}

// ---------------------------------------------------------------------------
// K5: support^T (swapped GEMM) + residual, both bf16 out, MFMA. [verified]
// ---------------------------------------------------------------------------
__global__ __launch_bounds__(256) void gemm2_mfma(
    const float* __restrict__ x,               // [B*N][128] fp32
    const unsigned short* __restrict__ Wt,     // [128f][128d]
    const unsigned short* __restrict__ rWt,    // [128f][128d]
    const float* __restrict__ rb,              // [128]
    unsigned short* __restrict__ supT,         // [B][128f][1024m]
    unsigned short* __restrict__ resid)        // [B*N][128]
{
    const int t = threadIdx.x, w = t >> 6, l = t & 63;
    const int ln = l & 15, kb = l >> 4;
    const int mblk = w >> 1, fhalf = w & 1;
    const int row0 = blockIdx.x * 32;
    const int b   = row0 >> 10;
    const int mg0 = row0 & 1023;

    const float* xrow = x + (size_t)(row0 + mblk * 16 + ln) * 128;
    short8 xa[4];
#pragma unroll
    for (int k = 0; k < 4; ++k) {
        float4 v0 = *(const float4*)(xrow + k * 32 + kb * 8);
        float4 v1 = *(const float4*)(xrow + k * 32 + kb * 8 + 4);
        short8 s;
        s[0] = (short)f2bf(v0.x); s[1] = (short)f2bf(v0.y);
        s[2] = (short)f2bf(v0.z); s[3] = (short)f2bf(v0.w);
        s[4] = (short)f2bf(v1.x); s[5] = (short)f2bf(v1.y);
        s[6] = (short)f2bf(v1.z); s[7] = (short)f2bf(v1.w);
        xa[k] = s;
    }

    f32x4 accS[4], accR[4];
#pragma unroll
    for (int i = 0; i < 4; ++i) { accS[i] = (f32x4){0,0,0,0}; accR[i] = (f32x4){0,0,0,0}; }

#pragma unroll
    for (int k = 0; k < 4; ++k) {
#pragma unroll
        for (int fb = 0; fb < 4; ++fb) {
            int fr = (fhalf * 4 + fb) * 16 + ln;
            short8 wa = *(const short8*)(Wt  + (size_t)fr * 128 + k * 32 + kb * 8);
            short8 wb = *(const short8*)(rWt + (size_t)fr * 128 + k * 32 + kb * 8);
            accS[fb] = __builtin_amdgcn_mfma_f32_16x16x32_bf16(wa, xa[k], accS[fb], 0, 0, 0);
            accR[fb] = __builtin_amdgcn_mfma_f32_16x16x32_bf16(xa[k], wb, accR[fb], 0, 0, 0);
        }
    }

#pragma unroll
    for (int fb = 0; fb < 4; ++fb) {
        int m = mg0 + mblk * 16 + ln;
#pragma unroll
        for (int i = 0; i < 4; ++i) {
            int f = (fhalf * 4 + fb) * 16 + kb * 4 + i;
            supT[((size_t)b * 128 + f) * 1024 + m] = f2bf(accS[fb][i]);
        }
    }
#pragma unroll
    for (int fb = 0; fb < 4; ++fb) {
        int f = (fhalf * 4 + fb) * 16 + ln;
        float rbf = rb[f];
#pragma unroll
        for (int i = 0; i < 4; ++i) {
            size_t row = (size_t)row0 + mblk * 16 + kb * 4 + i;
            resid[row * 128 + f] = f2bf(fmaxf(accR[fb][i] + rbf, 0.f));
        }
    }
}

// ---------------------------------------------------------------------------
// K6 ABLATION PROBE.  V=0 full (r6-identical, launched LAST -> correct out).
//   V=1 conv-only  (no loadT/score/mask; conv reads stale LDS)
//   V=2 score-only (no loadS/conv; acc stays 0)
//   V=3 no-adj     (mask = relu only; adj loads removed)
//   V=4 no-barrier (racy LDS; garbage values, overwritten later)
// Probes write garbage to d_out; final V0 launch overwrites -> deterministic.
// ---------------------------------------------------------------------------
template<int V>
__global__ __launch_bounds__(256, 4) void conv_probe(
    const unsigned short* __restrict__ src_bf,  // [P][N][64]
    const unsigned short* __restrict__ tgt_bf,  // [P][N][64]
    const unsigned short* __restrict__ adj_bf,  // [N][N]
    const unsigned short* __restrict__ supT,    // [B][128][1024]
    const unsigned short* __restrict__ resid,   // [B*N][128]
    const float* __restrict__ bias,             // [128]
    const int* __restrict__ cyc,                // [B]
    float* __restrict__ out)                    // [B][N][128]
{
    __shared__ unsigned short s_a[2][32][72] __attribute__((aligned(16)));

    const int i = blockIdx.x;                    // 0..1023, chunked XCD swizzle
    const int work = (i & 7) * 128 + (i >> 3);
    const int b  = work >> 5;
    const int n0 = (work & 31) * 32;

    const int t = threadIdx.x, w = t >> 6, l = t & 63;
    const int ln = l & 15, kb = l >> 4;
    const int p = ((cyc[b] % NPER) + NPER) % NPER;

    const int sn = w >> 1, sm = w & 1;   // score role
    const int cf = w;                     // conv role

    const unsigned short* srow = src_bf + ((size_t)p * N_ + n0 + sn * 16 + ln) * H_;
    const short8 sa0 = *(const short8*)(srow + kb * 8);
    const short8 sa1 = *(const short8*)(srow + 32 + kb * 8);

    const unsigned short* tbase = tgt_bf + (size_t)p * N_ * H_;
    const unsigned short* supb  = supT + (size_t)b * (size_t)F_ * N_;

    f32x4 acc[2][2];
#pragma unroll
    for (int r = 0; r < 2; ++r)
#pragma unroll
        for (int fb = 0; fb < 2; ++fb) acc[r][fb] = (f32x4){0, 0, 0, 0};

    auto loadT = [&](int m0, short8 (&tb)[2][2], unsigned short (&av)[2][4]) {
#pragma unroll
        for (int mt = 0; mt < 2; ++mt) {
            const unsigned short* trow =
                tbase + (size_t)(m0 + (sm * 2 + mt) * 16 + ln) * H_;
            tb[mt][0] = *(const short8*)(trow + kb * 8);
            tb[mt][1] = *(const short8*)(trow + 32 + kb * 8);
            const int ml = (sm * 2 + mt) * 16 + ln;
#pragma unroll
            for (int ii = 0; ii < 4; ++ii) {
                if constexpr (V == 3)
                    av[mt][ii] = 0x3F80;   // bf16 1.0
                else
                    av[mt][ii] = adj_bf[(size_t)(n0 + sn * 16 + kb * 4 + ii) * N_ + m0 + ml];
            }
        }
    };
    auto loadS = [&](int m0, short8 (&bs)[2][2]) {
#pragma unroll
        for (int ks = 0; ks < 2; ++ks)
#pragma unroll
            for (int fb = 0; fb < 2; ++fb)
                bs[ks][fb] = *(const short8*)(
                    supb + (size_t)(cf * 32 + fb * 16 + ln) * N_ + m0 + ks * 32 + kb * 8);
    };
    auto score = [&](const short8 (&tb)[2][2], const unsigned short (&av)[2][4], int wb) {
#pragma unroll
        for (int mt = 0; mt < 2; ++mt) {
            f32x4 c = (f32x4){0, 0, 0, 0};
            c = __builtin_amdgcn_mfma_f32_16x16x32_bf16(sa0, tb[mt][0], c, 0, 0, 0);
            c = __builtin_amdgcn_mfma_f32_16x16x32_bf16(sa1, tb[mt][1], c, 0, 0, 0);
            const int ml = (sm * 2 + mt) * 16 + ln;
#pragma unroll
            for (int ii = 0; ii < 4; ++ii) {
                float a2 = fmaxf(c[ii], 0.f) * bf2f(av[mt][ii]);
                s_a[wb][sn * 16 + kb * 4 + ii][ml] = f2bf_hw(a2);
            }
        }
    };
    auto conv = [&](int rb, const short8 (&bs)[2][2]) {
#pragma unroll
        for (int ks = 0; ks < 2; ++ks) {
            short8 af0 = *(const short8*)(&s_a[rb][ln][ks * 32 + kb * 8]);
            short8 af1 = *(const short8*)(&s_a[rb][16 + ln][ks * 32 + kb * 8]);
#pragma unroll
            for (int fb = 0; fb < 2; ++fb) {
                acc[0][fb] = __builtin_amdgcn_mfma_f32_16x16x32_bf16(af0, bs[ks][fb], acc[0][fb], 0, 0, 0);
                acc[1][fb] = __builtin_amdgcn_mfma_f32_16x16x32_bf16(af1, bs[ks][fb], acc[1][fb], 0, 0, 0);
            }
        }
    };
    auto barrier_lds = []() {
        if constexpr (V != 4) {
            asm volatile("s_waitcnt lgkmcnt(0)" ::: "memory");
            __builtin_amdgcn_s_barrier();
        }
    };

    short8 tbA[2][2], tbB[2][2];
    unsigned short adjA[2][4], adjB[2][4];
    short8 bsA[2][2], bsB[2][2];

    // prologue
    if constexpr (V != 1) {
        loadT(0, tbA, adjA);
        loadT(64, tbB, adjB);
    }
    if constexpr (V != 2) loadS(0, bsA);
    if constexpr (V != 1) score(tbA, adjA, 0);
    barrier_lds();

    for (int tt = 0; tt < 16; tt += 2) {
        if constexpr (V != 2) loadS((tt + 1) * 64, bsB);
        if constexpr (V != 1) { if (tt + 2 < 16) loadT((tt + 2) * 64, tbA, adjA); }
        __builtin_amdgcn_sched_barrier(0);
        if constexpr (V != 2) conv(0, bsA);
        if constexpr (V != 1) score(tbB, adjB, 1);
        barrier_lds();

        if constexpr (V != 2) { if (tt + 2 < 16) loadS((tt + 2) * 64, bsA); }
        if constexpr (V != 1) { if (tt + 3 < 16) loadT((tt + 3) * 64, tbB, adjB); }
        __builtin_amdgcn_sched_barrier(0);
        if constexpr (V != 2) conv(1, bsB);
        if constexpr (V != 1) {
            if (tt + 2 < 16) {
                score(tbA, adjA, 0);
                barrier_lds();
            }
        } else {
            barrier_lds();
        }
    }

    // epilogue: out = relu(conv + bias + residual)
#pragma unroll
    for (int r = 0; r < 2; ++r)
#pragma unroll
    for (int fb = 0; fb < 2; ++fb) {
        const int f = cf * 32 + fb * 16 + ln;
        const float bi = bias[f];
#pragma unroll
        for (int ii = 0; ii < 4; ++ii) {
            const int n = n0 + r * 16 + kb * 4 + ii;
            const size_t o = ((size_t)b * N_ + n) * F_ + f;
            out[o] = fmaxf(acc[r][fb][ii] + bi + bf2f(resid[o]), 0.f);
        }
    }
}

// ---------------------------------------------------------------------------
extern "C" void kernel_launch(void* const* d_in, const int* in_sizes, int n_in,
                              void* d_out, int out_size, void* d_ws, size_t ws_size,
                              hipStream_t stream) {
    const float* input_features = (const float*)d_in[0];
    const int*   cycle_indices  = (const int*)  d_in[1];
    const float* weight         = (const float*)d_in[2];
    const float* bias           = (const float*)d_in[3];
    const float* src_emb        = (const float*)d_in[4];
    const float* tgt_emb        = (const float*)d_in[5];
    const float* env_W          = (const float*)d_in[6];
    const float* env_b          = (const float*)d_in[7];
    const float* res_W          = (const float*)d_in[8];
    const float* res_b          = (const float*)d_in[9];
    const float* static_adj     = (const float*)d_in[10];
    const float* env_features   = (const float*)d_in[11];
    float* out = (float*)d_out;

    // workspace layout (~25.2 MiB)
    char* wsb = (char*)d_ws;
    unsigned short* src_bf = (unsigned short*)wsb;               // 3145728 B
    unsigned short* tgt_bf = src_bf + (size_t)NPER * N_ * H_;    // 3145728 B
    unsigned short* Wt     = tgt_bf + (size_t)NPER * N_ * H_;    // 32768 B
    unsigned short* rWt    = Wt + 16384;                         // 32768 B
    unsigned short* supT   = rWt + 16384;                        // 8388608 B
    unsigned short* resid  = supT + (size_t)B_ * F_ * N_;        // 8388608 B
    unsigned short* adj_bf = resid + (size_t)B_ * N_ * F_;       // 2097152 B

    prep_all<<<1408, 256, 0, stream>>>(
        src_emb, tgt_emb, env_features, env_W, env_b,
        static_adj, weight, res_W,
        src_bf, tgt_bf, adj_bf, Wt, rWt);

    gemm2_mfma<<<(B_ * N_) / 32, 256, 0, stream>>>(
        input_features, Wt, rWt, res_b, supT, resid);

    // ---- ablation probes (garbage out, overwritten by final V0) ----
    conv_probe<1><<<1024, 256, 0, stream>>>(src_bf, tgt_bf, adj_bf, supT, resid, bias, cycle_indices, out);
    conv_probe<2><<<1024, 256, 0, stream>>>(src_bf, tgt_bf, adj_bf, supT, resid, bias, cycle_indices, out);
    conv_probe<3><<<1024, 256, 0, stream>>>(src_bf, tgt_bf, adj_bf, supT, resid, bias, cycle_indices, out);
    conv_probe<4><<<1024, 256, 0, stream>>>(src_bf, tgt_bf, adj_bf, supT, resid, bias, cycle_indices, out);
    // ---- real computation ----
    conv_probe<0><<<1024, 256, 0, stream>>>(src_bf, tgt_bf, adj_bf, supT, resid, bias, cycle_indices, out);
}

// Round 9
// 65.533 us; speedup vs baseline: 4.5004x; 4.5004x over previous
//
#include <hip/hip_runtime.h>
#include <hip/hip_bf16.h>

#define NPER 24
#define B_ 32
#define N_ 1024
#define F_ 128
#define H_ 64
#define E_ 16

typedef __attribute__((ext_vector_type(8))) short short8;
typedef __attribute__((ext_vector_type(4))) float f32x4;

#define GLD16(g, l) __builtin_amdgcn_global_load_lds( \
    (const __attribute__((address_space(1))) void*)(g), \
    (__attribute__((address_space(3))) void*)(l), 16, 0, 0)

static __device__ __forceinline__ unsigned short f2bf(float x) {
    union { float f; unsigned u; } v; v.f = x;
    unsigned r = v.u + 0x7fffu + ((v.u >> 16) & 1u);   // RNE
    return (unsigned short)(r >> 16);
}
static __device__ __forceinline__ float bf2f(unsigned short h) {
    union { unsigned u; float f; } v; v.u = ((unsigned)h) << 16; return v.f;
}
static __device__ __forceinline__ unsigned short f2bf_hw(float x) {
    __hip_bfloat16 h = __float2bfloat16(x);
    return *(unsigned short*)&h;
}

// ---------------------------------------------------------------------------
// P1: all prep in one launch.  [r7-verified]
// ---------------------------------------------------------------------------
__global__ __launch_bounds__(256) void prep_all(
    const float* __restrict__ src_emb, const float* __restrict__ tgt_emb,
    const float* __restrict__ env_features, const float* __restrict__ env_W,
    const float* __restrict__ env_b,
    const float* __restrict__ adj, const float* __restrict__ W,
    const float* __restrict__ rW,
    unsigned short* __restrict__ src_bf, unsigned short* __restrict__ tgt_bf,
    unsigned short* __restrict__ adj_bf, unsigned short* __restrict__ Wt,
    unsigned short* __restrict__ rWt)
{
    const int bid = blockIdx.x;
    if (bid < 256) {
        const int idx = bid * 256 + threadIdx.x;   // 0..65535
        const int n = idx >> 6, h = idx & 63;
        float e = env_b[h];
#pragma unroll
        for (int k = 0; k < E_; ++k)
            e = fmaf(env_features[n * E_ + k], env_W[k * H_ + h], e);
        e = fmaxf(e, 0.f);
#pragma unroll 4
        for (int p = 0; p < NPER; ++p) {
            const size_t off = (size_t)p * (N_ * H_) + idx;
            src_bf[off] = f2bf(src_emb[off] + e);
            tgt_bf[off] = f2bf(tgt_emb[off] + e);
        }
    } else if (bid < 1280) {
        const size_t i = ((size_t)(bid - 256) * 256 + threadIdx.x) * 4;
        float4 v = *(const float4*)(adj + i);
        ushort4 o;
        o.x = f2bf(v.x); o.y = f2bf(v.y); o.z = f2bf(v.z); o.w = f2bf(v.w);
        *(ushort4*)(adj_bf + i) = o;
    } else {
        const int idx = (bid - 1280) * 256 + threadIdx.x;   // 0..32767
        const int which = idx >> 14, j = idx & 16383;
        const int f = j >> 7, d = j & 127;
        if (which == 0) Wt[f * 128 + d]  = f2bf(W[d * 128 + f]);
        else            rWt[f * 128 + d] = f2bf(rW[d * 128 + f]);
    }
}

// ---------------------------------------------------------------------------
// K5: support^T (swapped GEMM) + residual, both bf16 out, MFMA. [verified]
// ---------------------------------------------------------------------------
__global__ __launch_bounds__(256) void gemm2_mfma(
    const float* __restrict__ x,               // [B*N][128] fp32
    const unsigned short* __restrict__ Wt,     // [128f][128d]
    const unsigned short* __restrict__ rWt,    // [128f][128d]
    const float* __restrict__ rb,              // [128]
    unsigned short* __restrict__ supT,         // [B][128f][1024m]
    unsigned short* __restrict__ resid)        // [B*N][128]
{
    const int t = threadIdx.x, w = t >> 6, l = t & 63;
    const int ln = l & 15, kb = l >> 4;
    const int mblk = w >> 1, fhalf = w & 1;
    const int row0 = blockIdx.x * 32;
    const int b   = row0 >> 10;
    const int mg0 = row0 & 1023;

    const float* xrow = x + (size_t)(row0 + mblk * 16 + ln) * 128;
    short8 xa[4];
#pragma unroll
    for (int k = 0; k < 4; ++k) {
        float4 v0 = *(const float4*)(xrow + k * 32 + kb * 8);
        float4 v1 = *(const float4*)(xrow + k * 32 + kb * 8 + 4);
        short8 s;
        s[0] = (short)f2bf(v0.x); s[1] = (short)f2bf(v0.y);
        s[2] = (short)f2bf(v0.z); s[3] = (short)f2bf(v0.w);
        s[4] = (short)f2bf(v1.x); s[5] = (short)f2bf(v1.y);
        s[6] = (short)f2bf(v1.z); s[7] = (short)f2bf(v1.w);
        xa[k] = s;
    }

    f32x4 accS[4], accR[4];
#pragma unroll
    for (int i = 0; i < 4; ++i) { accS[i] = (f32x4){0,0,0,0}; accR[i] = (f32x4){0,0,0,0}; }

#pragma unroll
    for (int k = 0; k < 4; ++k) {
#pragma unroll
        for (int fb = 0; fb < 4; ++fb) {
            int fr = (fhalf * 4 + fb) * 16 + ln;
            short8 wa = *(const short8*)(Wt  + (size_t)fr * 128 + k * 32 + kb * 8);
            short8 wb = *(const short8*)(rWt + (size_t)fr * 128 + k * 32 + kb * 8);
            accS[fb] = __builtin_amdgcn_mfma_f32_16x16x32_bf16(wa, xa[k], accS[fb], 0, 0, 0);
            accR[fb] = __builtin_amdgcn_mfma_f32_16x16x32_bf16(xa[k], wb, accR[fb], 0, 0, 0);
        }
    }

#pragma unroll
    for (int fb = 0; fb < 4; ++fb) {
        int m = mg0 + mblk * 16 + ln;
#pragma unroll
        for (int i = 0; i < 4; ++i) {
            int f = (fhalf * 4 + fb) * 16 + kb * 4 + i;
            supT[((size_t)b * 128 + f) * 1024 + m] = f2bf(accS[fb][i]);
        }
    }
#pragma unroll
    for (int fb = 0; fb < 4; ++fb) {
        int f = (fhalf * 4 + fb) * 16 + ln;
        float rbf = rb[f];
#pragma unroll
        for (int i = 0; i < 4; ++i) {
            size_t row = (size_t)row0 + mblk * 16 + kb * 4 + i;
            resid[row * 128 + f] = f2bf(fmaxf(accR[fb][i] + rbf, 0.f));
        }
    }
}

// ---------------------------------------------------------------------------
// K6: m97-style staged version. Block = (b, 64-row n-tile), 256 thr / 4 waves,
// grid 512 (XCD-swizzled). Per 64-m chunk: tgt (8KB) + supT (16KB) staged via
// coalesced global_load_lds into double-buffered LINEAR LDS; masked-A tile in
// padded [64][72] LDS (VALU ds_write_b64). adj per-lane ushort4, prefetched
// one chunk ahead. Score: mfma(tgt,src) -> C[m][n], m = kb*4+i (b64 A-write).
// Conv: A-frags + supT B-frags from LDS. 2 raw barriers/chunk:
//   lgkmcnt(0)+bar after score (A visible), vmcnt(0)+bar at chunk end.
// ---------------------------------------------------------------------------
__global__ __launch_bounds__(256, 2) void conv_mfma(
    const unsigned short* __restrict__ src_bf,  // [P][N][64]
    const unsigned short* __restrict__ tgt_bf,  // [P][N][64]
    const unsigned short* __restrict__ adj_bf,  // [N][N]
    const unsigned short* __restrict__ supT,    // [B][128][1024]
    const unsigned short* __restrict__ resid,   // [B*N][128]
    const float* __restrict__ bias,             // [128]
    const int* __restrict__ cyc,                // [B]
    float* __restrict__ out)                    // [B][N][128]
{
    __shared__ unsigned short s_tgt[2][64 * 64] __attribute__((aligned(16)));
    __shared__ unsigned short s_sup[2][128 * 64] __attribute__((aligned(16)));
    __shared__ unsigned short s_a[64][72] __attribute__((aligned(16)));

    const int i = blockIdx.x;                    // 0..511
    const int work = (i & 7) * 64 + (i >> 3);    // XCD k: 2 consecutive b's
    const int b  = work >> 4;
    const int n0 = (work & 15) * 64;

    const int t = threadIdx.x, w = t >> 6, l = t & 63;
    const int ln = l & 15, kb = l >> 4;
    const int p = ((cyc[b] % NPER) + NPER) % NPER;

    const int sn = w >> 1, sm = w & 1;   // score: 32n x 32m quarter per wave
    const int cf = w;                    // conv: 32 f columns per wave

    // hoisted src fragments (score B-operand): col n = ln, k = h
    short8 sfrag[2][2];
#pragma unroll
    for (int nt = 0; nt < 2; ++nt)
#pragma unroll
        for (int k2 = 0; k2 < 2; ++k2)
            sfrag[nt][k2] = *(const short8*)(
                src_bf + ((size_t)p * N_ + n0 + sn * 32 + nt * 16 + ln) * H_ + k2 * 32 + kb * 8);

    const unsigned short* tgtg = tgt_bf + (size_t)p * N_ * H_;
    const unsigned short* supg = supT + (size_t)b * F_ * N_;

    f32x4 acc[4][2];
#pragma unroll
    for (int q = 0; q < 4; ++q)
#pragma unroll
        for (int fb = 0; fb < 2; ++fb) acc[q][fb] = (f32x4){0, 0, 0, 0};

    auto stage = [&](int buf, int m0) {
        // tgt tile: 64 rows x 128B, linear; row = te>>3, 16B chunk = te&7
#pragma unroll
        for (int j = 0; j < 2; ++j) {
            const int te = j * 256 + t;
            GLD16(tgtg + (size_t)(m0 + (te >> 3)) * H_ + (te & 7) * 8,
                  &s_tgt[buf][te * 8]);
        }
        // supT tile: 128 rows x 128B (64 m elems of each f row)
#pragma unroll
        for (int j = 0; j < 4; ++j) {
            const int te = j * 256 + t;
            GLD16(supg + (size_t)(te >> 3) * N_ + m0 + (te & 7) * 8,
                  &s_sup[buf][te * 8]);
        }
    };

    auto loadAdj = [&](int m0, ushort4 (&av)[2][2]) {
#pragma unroll
        for (int nt = 0; nt < 2; ++nt)
#pragma unroll
            for (int mt = 0; mt < 2; ++mt)
                av[nt][mt] = *(const ushort4*)(
                    adj_bf + (size_t)(n0 + sn * 32 + nt * 16 + ln) * N_
                           + m0 + sm * 32 + mt * 16 + kb * 4);
    };

    auto score = [&](int buf, const ushort4 (&av)[2][2]) {
        short8 tf[2][2];
#pragma unroll
        for (int mt = 0; mt < 2; ++mt)
#pragma unroll
            for (int k2 = 0; k2 < 2; ++k2)
                tf[mt][k2] = *(const short8*)(
                    &s_tgt[buf][(sm * 32 + mt * 16 + ln) * H_ + k2 * 32 + kb * 8]);
#pragma unroll
        for (int nt = 0; nt < 2; ++nt)
#pragma unroll
            for (int mt = 0; mt < 2; ++mt) {
                f32x4 c = (f32x4){0, 0, 0, 0};
                c = __builtin_amdgcn_mfma_f32_16x16x32_bf16(tf[mt][0], sfrag[nt][0], c, 0, 0, 0);
                c = __builtin_amdgcn_mfma_f32_16x16x32_bf16(tf[mt][1], sfrag[nt][1], c, 0, 0, 0);
                // C[m][n]: col n = ln, row m = kb*4 + i  -> 4 consecutive m
                const int nl = sn * 32 + nt * 16 + ln;
                const int ml = sm * 32 + mt * 16 + kb * 4;
                const ushort4 a = av[nt][mt];
                uint2 q;
                q.x = (unsigned)f2bf_hw(fmaxf(c[0], 0.f) * bf2f(a.x))
                    | ((unsigned)f2bf_hw(fmaxf(c[1], 0.f) * bf2f(a.y)) << 16);
                q.y = (unsigned)f2bf_hw(fmaxf(c[2], 0.f) * bf2f(a.z))
                    | ((unsigned)f2bf_hw(fmaxf(c[3], 0.f) * bf2f(a.w)) << 16);
                *(uint2*)(&s_a[nl][ml]) = q;
            }
    };

    auto conv = [&](int buf) {
#pragma unroll
        for (int ks = 0; ks < 2; ++ks) {
            short8 bfrag[2];
#pragma unroll
            for (int fb = 0; fb < 2; ++fb)
                bfrag[fb] = *(const short8*)(
                    &s_sup[buf][(cf * 32 + fb * 16 + ln) * 64 + ks * 32 + kb * 8]);
#pragma unroll
            for (int nt2 = 0; nt2 < 4; ++nt2) {
                short8 af = *(const short8*)(&s_a[nt2 * 16 + ln][ks * 32 + kb * 8]);
#pragma unroll
                for (int fb = 0; fb < 2; ++fb)
                    acc[nt2][fb] = __builtin_amdgcn_mfma_f32_16x16x32_bf16(
                        af, bfrag[fb], acc[nt2][fb], 0, 0, 0);
            }
        }
    };

    auto bar_lgkm = []() {
        asm volatile("s_waitcnt lgkmcnt(0)" ::: "memory");
        __builtin_amdgcn_s_barrier();
    };
    auto bar_vm0 = []() {
        asm volatile("s_waitcnt vmcnt(0) lgkmcnt(0)" ::: "memory");
        __builtin_amdgcn_s_barrier();
    };

    ushort4 avA[2][2], avB[2][2];

    stage(0, 0);
    loadAdj(0, avA);
    bar_vm0();

    for (int tt = 0; tt < 16; tt += 2) {
        // even chunk: read buf0; prefetch chunk tt+1 into buf1
        stage(1, (tt + 1) * 64);
        loadAdj((tt + 1) * 64, avB);
        score(0, avA);
        bar_lgkm();
        conv(0);
        bar_vm0();

        // odd chunk: read buf1; prefetch chunk tt+2 into buf0
        if (tt + 2 < 16) {
            stage(0, (tt + 2) * 64);
            loadAdj((tt + 2) * 64, avA);
        }
        score(1, avB);
        bar_lgkm();
        conv(1);
        bar_vm0();
    }

    // epilogue: out = relu(conv + bias + residual)
#pragma unroll
    for (int nt2 = 0; nt2 < 4; ++nt2)
#pragma unroll
    for (int fb = 0; fb < 2; ++fb) {
        const int f = cf * 32 + fb * 16 + ln;
        const float bi = bias[f];
#pragma unroll
        for (int ii = 0; ii < 4; ++ii) {
            const int n = n0 + nt2 * 16 + kb * 4 + ii;
            const size_t o = ((size_t)b * N_ + n) * F_ + f;
            out[o] = fmaxf(acc[nt2][fb][ii] + bi + bf2f(resid[o]), 0.f);
        }
    }
}

// ---------------------------------------------------------------------------
extern "C" void kernel_launch(void* const* d_in, const int* in_sizes, int n_in,
                              void* d_out, int out_size, void* d_ws, size_t ws_size,
                              hipStream_t stream) {
    const float* input_features = (const float*)d_in[0];
    const int*   cycle_indices  = (const int*)  d_in[1];
    const float* weight         = (const float*)d_in[2];
    const float* bias           = (const float*)d_in[3];
    const float* src_emb        = (const float*)d_in[4];
    const float* tgt_emb        = (const float*)d_in[5];
    const float* env_W          = (const float*)d_in[6];
    const float* env_b          = (const float*)d_in[7];
    const float* res_W          = (const float*)d_in[8];
    const float* res_b          = (const float*)d_in[9];
    const float* static_adj     = (const float*)d_in[10];
    const float* env_features   = (const float*)d_in[11];
    float* out = (float*)d_out;

    // workspace layout (~25.2 MiB)
    char* wsb = (char*)d_ws;
    unsigned short* src_bf = (unsigned short*)wsb;               // 3145728 B
    unsigned short* tgt_bf = src_bf + (size_t)NPER * N_ * H_;    // 3145728 B
    unsigned short* Wt     = tgt_bf + (size_t)NPER * N_ * H_;    // 32768 B
    unsigned short* rWt    = Wt + 16384;                         // 32768 B
    unsigned short* supT   = rWt + 16384;                        // 8388608 B
    unsigned short* resid  = supT + (size_t)B_ * F_ * N_;        // 8388608 B
    unsigned short* adj_bf = resid + (size_t)B_ * N_ * F_;       // 2097152 B

    prep_all<<<1408, 256, 0, stream>>>(
        src_emb, tgt_emb, env_features, env_W, env_b,
        static_adj, weight, res_W,
        src_bf, tgt_bf, adj_bf, Wt, rWt);

    gemm2_mfma<<<(B_ * N_) / 32, 256, 0, stream>>>(
        input_features, Wt, rWt, res_b, supT, resid);

    conv_mfma<<<512, 256, 0, stream>>>(
        src_bf, tgt_bf, adj_bf, supT, resid, bias, cycle_indices, out);
}

// Round 10
// 64.106 us; speedup vs baseline: 4.6006x; 1.0223x over previous
//
#include <hip/hip_runtime.h>
#include <hip/hip_bf16.h>

#define NPER 24
#define B_ 32
#define N_ 1024
#define F_ 128
#define H_ 64
#define E_ 16

typedef __attribute__((ext_vector_type(8))) short short8;
typedef __attribute__((ext_vector_type(4))) float f32x4;

#define GLD16(g, l) __builtin_amdgcn_global_load_lds( \
    (const __attribute__((address_space(1))) void*)(g), \
    (__attribute__((address_space(3))) void*)(l), 16, 0, 0)

static __device__ __forceinline__ unsigned short f2bf(float x) {
    union { float f; unsigned u; } v; v.f = x;
    unsigned r = v.u + 0x7fffu + ((v.u >> 16) & 1u);   // RNE
    return (unsigned short)(r >> 16);
}
static __device__ __forceinline__ float bf2f(unsigned short h) {
    union { unsigned u; float f; } v; v.u = ((unsigned)h) << 16; return v.f;
}
static __device__ __forceinline__ unsigned short f2bf_hw(float x) {
    __hip_bfloat16 h = __float2bfloat16(x);
    return *(unsigned short*)&h;
}

// ---------------------------------------------------------------------------
// P1: all prep in one launch.  [r7-verified]
// ---------------------------------------------------------------------------
__global__ __launch_bounds__(256) void prep_all(
    const float* __restrict__ src_emb, const float* __restrict__ tgt_emb,
    const float* __restrict__ env_features, const float* __restrict__ env_W,
    const float* __restrict__ env_b,
    const float* __restrict__ adj, const float* __restrict__ W,
    const float* __restrict__ rW,
    unsigned short* __restrict__ src_bf, unsigned short* __restrict__ tgt_bf,
    unsigned short* __restrict__ adj_bf, unsigned short* __restrict__ Wt,
    unsigned short* __restrict__ rWt)
{
    const int bid = blockIdx.x;
    if (bid < 256) {
        const int idx = bid * 256 + threadIdx.x;   // 0..65535
        const int n = idx >> 6, h = idx & 63;
        float e = env_b[h];
#pragma unroll
        for (int k = 0; k < E_; ++k)
            e = fmaf(env_features[n * E_ + k], env_W[k * H_ + h], e);
        e = fmaxf(e, 0.f);
#pragma unroll 4
        for (int p = 0; p < NPER; ++p) {
            const size_t off = (size_t)p * (N_ * H_) + idx;
            src_bf[off] = f2bf(src_emb[off] + e);
            tgt_bf[off] = f2bf(tgt_emb[off] + e);
        }
    } else if (bid < 1280) {
        const size_t i = ((size_t)(bid - 256) * 256 + threadIdx.x) * 4;
        float4 v = *(const float4*)(adj + i);
        ushort4 o;
        o.x = f2bf(v.x); o.y = f2bf(v.y); o.z = f2bf(v.z); o.w = f2bf(v.w);
        *(ushort4*)(adj_bf + i) = o;
    } else {
        const int idx = (bid - 1280) * 256 + threadIdx.x;   // 0..32767
        const int which = idx >> 14, j = idx & 16383;
        const int f = j >> 7, d = j & 127;
        if (which == 0) Wt[f * 128 + d]  = f2bf(W[d * 128 + f]);
        else            rWt[f * 128 + d] = f2bf(rW[d * 128 + f]);
    }
}

// ---------------------------------------------------------------------------
// K5: support^T (swapped GEMM) + residual, both bf16 out, MFMA. [verified]
// ---------------------------------------------------------------------------
__global__ __launch_bounds__(256) void gemm2_mfma(
    const float* __restrict__ x,               // [B*N][128] fp32
    const unsigned short* __restrict__ Wt,     // [128f][128d]
    const unsigned short* __restrict__ rWt,    // [128f][128d]
    const float* __restrict__ rb,              // [128]
    unsigned short* __restrict__ supT,         // [B][128f][1024m]
    unsigned short* __restrict__ resid)        // [B*N][128]
{
    const int t = threadIdx.x, w = t >> 6, l = t & 63;
    const int ln = l & 15, kb = l >> 4;
    const int mblk = w >> 1, fhalf = w & 1;
    const int row0 = blockIdx.x * 32;
    const int b   = row0 >> 10;
    const int mg0 = row0 & 1023;

    const float* xrow = x + (size_t)(row0 + mblk * 16 + ln) * 128;
    short8 xa[4];
#pragma unroll
    for (int k = 0; k < 4; ++k) {
        float4 v0 = *(const float4*)(xrow + k * 32 + kb * 8);
        float4 v1 = *(const float4*)(xrow + k * 32 + kb * 8 + 4);
        short8 s;
        s[0] = (short)f2bf(v0.x); s[1] = (short)f2bf(v0.y);
        s[2] = (short)f2bf(v0.z); s[3] = (short)f2bf(v0.w);
        s[4] = (short)f2bf(v1.x); s[5] = (short)f2bf(v1.y);
        s[6] = (short)f2bf(v1.z); s[7] = (short)f2bf(v1.w);
        xa[k] = s;
    }

    f32x4 accS[4], accR[4];
#pragma unroll
    for (int i = 0; i < 4; ++i) { accS[i] = (f32x4){0,0,0,0}; accR[i] = (f32x4){0,0,0,0}; }

#pragma unroll
    for (int k = 0; k < 4; ++k) {
#pragma unroll
        for (int fb = 0; fb < 4; ++fb) {
            int fr = (fhalf * 4 + fb) * 16 + ln;
            short8 wa = *(const short8*)(Wt  + (size_t)fr * 128 + k * 32 + kb * 8);
            short8 wb = *(const short8*)(rWt + (size_t)fr * 128 + k * 32 + kb * 8);
            accS[fb] = __builtin_amdgcn_mfma_f32_16x16x32_bf16(wa, xa[k], accS[fb], 0, 0, 0);
            accR[fb] = __builtin_amdgcn_mfma_f32_16x16x32_bf16(xa[k], wb, accR[fb], 0, 0, 0);
        }
    }

#pragma unroll
    for (int fb = 0; fb < 4; ++fb) {
        int m = mg0 + mblk * 16 + ln;
#pragma unroll
        for (int i = 0; i < 4; ++i) {
            int f = (fhalf * 4 + fb) * 16 + kb * 4 + i;
            supT[((size_t)b * 128 + f) * 1024 + m] = f2bf(accS[fb][i]);
        }
    }
#pragma unroll
    for (int fb = 0; fb < 4; ++fb) {
        int f = (fhalf * 4 + fb) * 16 + ln;
        float rbf = rb[f];
#pragma unroll
        for (int i = 0; i < 4; ++i) {
            size_t row = (size_t)row0 + mblk * 16 + kb * 4 + i;
            resid[row * 128 + f] = f2bf(fmaxf(accR[fb][i] + rbf, 0.f));
        }
    }
}

// ---------------------------------------------------------------------------
// K6: staged + T2 XOR-swizzle. Block = (b, 64-row n-tile), 256 thr / 4 waves,
// grid 512 (XCD-swizzled). Per 64-m chunk: tgt (8KB) + supT (16KB) staged via
// global_load_lds into double-buffered LDS. Rule #21: gload_lds writes
// LINEARLY, so the st-style swizzle (chunk ^= row&7, 16B chunks) is applied
// by pre-swizzling the per-lane GLOBAL source address, and the same XOR on
// every ds_read_b128. Coalescing preserved (each 8-lane group covers its
// row's full 128B, permuted). Kills the 16-way conflict of 128B-stride rows.
// ---------------------------------------------------------------------------
__global__ __launch_bounds__(256, 2) void conv_mfma(
    const unsigned short* __restrict__ src_bf,  // [P][N][64]
    const unsigned short* __restrict__ tgt_bf,  // [P][N][64]
    const unsigned short* __restrict__ adj_bf,  // [N][N]
    const unsigned short* __restrict__ supT,    // [B][128][1024]
    const unsigned short* __restrict__ resid,   // [B*N][128]
    const float* __restrict__ bias,             // [128]
    const int* __restrict__ cyc,                // [B]
    float* __restrict__ out)                    // [B][N][128]
{
    __shared__ unsigned short s_tgt[2][64 * 64] __attribute__((aligned(16)));
    __shared__ unsigned short s_sup[2][128 * 64] __attribute__((aligned(16)));
    __shared__ unsigned short s_a[64][72] __attribute__((aligned(16)));

    const int i = blockIdx.x;                    // 0..511
    const int work = (i & 7) * 64 + (i >> 3);    // XCD k: 2 consecutive b's
    const int b  = work >> 4;
    const int n0 = (work & 15) * 64;

    const int t = threadIdx.x, w = t >> 6, l = t & 63;
    const int ln = l & 15, kb = l >> 4;
    const int p = ((cyc[b] % NPER) + NPER) % NPER;

    const int sn = w >> 1, sm = w & 1;   // score: 32n x 32m quarter per wave
    const int cf = w;                    // conv: 32 f columns per wave

    // hoisted src fragments (score B-operand): col n = ln, k = h
    short8 sfrag[2][2];
#pragma unroll
    for (int nt = 0; nt < 2; ++nt)
#pragma unroll
        for (int k2 = 0; k2 < 2; ++k2)
            sfrag[nt][k2] = *(const short8*)(
                src_bf + ((size_t)p * N_ + n0 + sn * 32 + nt * 16 + ln) * H_ + k2 * 32 + kb * 8);

    const unsigned short* tgtg = tgt_bf + (size_t)p * N_ * H_;
    const unsigned short* supg = supT + (size_t)b * F_ * N_;

    f32x4 acc[4][2];
#pragma unroll
    for (int q = 0; q < 4; ++q)
#pragma unroll
        for (int fb = 0; fb < 2; ++fb) acc[q][fb] = (f32x4){0, 0, 0, 0};

    auto stage = [&](int buf, int m0) {
        // tgt tile: 64 rows x 8 chunks(16B); source chunk pre-swizzled
#pragma unroll
        for (int j = 0; j < 2; ++j) {
            const int te = j * 256 + t;
            const int r = te >> 3, c = te & 7;
            GLD16(tgtg + (size_t)(m0 + r) * H_ + (c ^ (r & 7)) * 8,
                  &s_tgt[buf][te * 8]);
        }
        // supT tile: 128 rows x 8 chunks(16B)
#pragma unroll
        for (int j = 0; j < 4; ++j) {
            const int te = j * 256 + t;
            const int r = te >> 3, c = te & 7;
            GLD16(supg + (size_t)r * N_ + m0 + (c ^ (r & 7)) * 8,
                  &s_sup[buf][te * 8]);
        }
    };

    auto loadAdj = [&](int m0, ushort4 (&av)[2][2]) {
#pragma unroll
        for (int nt = 0; nt < 2; ++nt)
#pragma unroll
            for (int mt = 0; mt < 2; ++mt)
                av[nt][mt] = *(const ushort4*)(
                    adj_bf + (size_t)(n0 + sn * 32 + nt * 16 + ln) * N_
                           + m0 + sm * 32 + mt * 16 + kb * 4);
    };

    auto score = [&](int buf, const ushort4 (&av)[2][2]) {
        short8 tf[2][2];
#pragma unroll
        for (int mt = 0; mt < 2; ++mt)
#pragma unroll
            for (int k2 = 0; k2 < 2; ++k2) {
                const int trow = sm * 32 + mt * 16 + ln;
                tf[mt][k2] = *(const short8*)(
                    &s_tgt[buf][trow * 64 + ((k2 * 4 + kb) ^ (ln & 7)) * 8]);
            }
#pragma unroll
        for (int nt = 0; nt < 2; ++nt)
#pragma unroll
            for (int mt = 0; mt < 2; ++mt) {
                f32x4 c = (f32x4){0, 0, 0, 0};
                c = __builtin_amdgcn_mfma_f32_16x16x32_bf16(tf[mt][0], sfrag[nt][0], c, 0, 0, 0);
                c = __builtin_amdgcn_mfma_f32_16x16x32_bf16(tf[mt][1], sfrag[nt][1], c, 0, 0, 0);
                // C[m][n]: col n = ln, row m = kb*4 + i  -> 4 consecutive m
                const int nl = sn * 32 + nt * 16 + ln;
                const int ml = sm * 32 + mt * 16 + kb * 4;
                const ushort4 a = av[nt][mt];
                uint2 q;
                q.x = (unsigned)f2bf_hw(fmaxf(c[0], 0.f) * bf2f(a.x))
                    | ((unsigned)f2bf_hw(fmaxf(c[1], 0.f) * bf2f(a.y)) << 16);
                q.y = (unsigned)f2bf_hw(fmaxf(c[2], 0.f) * bf2f(a.z))
                    | ((unsigned)f2bf_hw(fmaxf(c[3], 0.f) * bf2f(a.w)) << 16);
                *(uint2*)(&s_a[nl][ml]) = q;
            }
    };

    auto conv = [&](int buf) {
#pragma unroll
        for (int ks = 0; ks < 2; ++ks) {
            short8 bfrag[2];
#pragma unroll
            for (int fb = 0; fb < 2; ++fb) {
                const int frow = cf * 32 + fb * 16 + ln;
                bfrag[fb] = *(const short8*)(
                    &s_sup[buf][frow * 64 + ((ks * 4 + kb) ^ (ln & 7)) * 8]);
            }
#pragma unroll
            for (int nt2 = 0; nt2 < 4; ++nt2) {
                short8 af = *(const short8*)(&s_a[nt2 * 16 + ln][ks * 32 + kb * 8]);
#pragma unroll
                for (int fb = 0; fb < 2; ++fb)
                    acc[nt2][fb] = __builtin_amdgcn_mfma_f32_16x16x32_bf16(
                        af, bfrag[fb], acc[nt2][fb], 0, 0, 0);
            }
        }
    };

    auto bar_lgkm = []() {
        asm volatile("s_waitcnt lgkmcnt(0)" ::: "memory");
        __builtin_amdgcn_s_barrier();
    };
    auto bar_vm0 = []() {
        asm volatile("s_waitcnt vmcnt(0) lgkmcnt(0)" ::: "memory");
        __builtin_amdgcn_s_barrier();
    };

    ushort4 avA[2][2], avB[2][2];

    stage(0, 0);
    loadAdj(0, avA);
    bar_vm0();

    for (int tt = 0; tt < 16; tt += 2) {
        // even chunk: read buf0; prefetch chunk tt+1 into buf1
        stage(1, (tt + 1) * 64);
        loadAdj((tt + 1) * 64, avB);
        score(0, avA);
        bar_lgkm();
        conv(0);
        bar_vm0();

        // odd chunk: read buf1; prefetch chunk tt+2 into buf0
        if (tt + 2 < 16) {
            stage(0, (tt + 2) * 64);
            loadAdj((tt + 2) * 64, avA);
        }
        score(1, avB);
        bar_lgkm();
        conv(1);
        bar_vm0();
    }

    // epilogue: out = relu(conv + bias + residual)
#pragma unroll
    for (int nt2 = 0; nt2 < 4; ++nt2)
#pragma unroll
    for (int fb = 0; fb < 2; ++fb) {
        const int f = cf * 32 + fb * 16 + ln;
        const float bi = bias[f];
#pragma unroll
        for (int ii = 0; ii < 4; ++ii) {
            const int n = n0 + nt2 * 16 + kb * 4 + ii;
            const size_t o = ((size_t)b * N_ + n) * F_ + f;
            out[o] = fmaxf(acc[nt2][fb][ii] + bi + bf2f(resid[o]), 0.f);
        }
    }
}

// ---------------------------------------------------------------------------
extern "C" void kernel_launch(void* const* d_in, const int* in_sizes, int n_in,
                              void* d_out, int out_size, void* d_ws, size_t ws_size,
                              hipStream_t stream) {
    const float* input_features = (const float*)d_in[0];
    const int*   cycle_indices  = (const int*)  d_in[1];
    const float* weight         = (const float*)d_in[2];
    const float* bias           = (const float*)d_in[3];
    const float* src_emb        = (const float*)d_in[4];
    const float* tgt_emb        = (const float*)d_in[5];
    const float* env_W          = (const float*)d_in[6];
    const float* env_b          = (const float*)d_in[7];
    const float* res_W          = (const float*)d_in[8];
    const float* res_b          = (const float*)d_in[9];
    const float* static_adj     = (const float*)d_in[10];
    const float* env_features   = (const float*)d_in[11];
    float* out = (float*)d_out;

    // workspace layout (~25.2 MiB)
    char* wsb = (char*)d_ws;
    unsigned short* src_bf = (unsigned short*)wsb;               // 3145728 B
    unsigned short* tgt_bf = src_bf + (size_t)NPER * N_ * H_;    // 3145728 B
    unsigned short* Wt     = tgt_bf + (size_t)NPER * N_ * H_;    // 32768 B
    unsigned short* rWt    = Wt + 16384;                         // 32768 B
    unsigned short* supT   = rWt + 16384;                        // 8388608 B
    unsigned short* resid  = supT + (size_t)B_ * F_ * N_;        // 8388608 B
    unsigned short* adj_bf = resid + (size_t)B_ * N_ * F_;       // 2097152 B

    prep_all<<<1408, 256, 0, stream>>>(
        src_emb, tgt_emb, env_features, env_W, env_b,
        static_adj, weight, res_W,
        src_bf, tgt_bf, adj_bf, Wt, rWt);

    gemm2_mfma<<<(B_ * N_) / 32, 256, 0, stream>>>(
        input_features, Wt, rWt, res_b, supT, resid);

    conv_mfma<<<512, 256, 0, stream>>>(
        src_bf, tgt_bf, adj_bf, supT, resid, bias, cycle_indices, out);
}